// Round 3
// baseline (91.531 us; speedup 1.0000x reference)
//
#include <hip/hip_runtime.h>
#include <math.h>

#define VOCAB  100000
#define DIM    128
#define BATCH  16384
#define NEG    10
#define NBLOCK (BATCH / 8)   // 2048 blocks, 8 rows each

// Numerically stable log-sigmoid: log(1/(1+e^-x)) = min(x,0) - log1p(e^-|x|)
__device__ __forceinline__ float logsig(float x) {
    float ax = fabsf(x);
    float l  = log1pf(expf(-ax));
    return (x >= 0.0f) ? -l : (x - l);
}

// Fused kernel: 32 lanes per batch row (float4/lane), 2 rows/wave, 8 rows per
// 256-thread block, 2048 blocks = 8192 waves. Tail: last-block-done reduction
// (deterministic; counter zeroed by a 4-byte memset each call).
__global__ __launch_bounds__(256) void sg_fused_kernel(
    const float* __restrict__ focus_W,
    const float* __restrict__ context_W,
    const int*   __restrict__ focus_idx,
    const int*   __restrict__ context_idx,
    const int*   __restrict__ neg_idx,
    float*       __restrict__ partial,
    unsigned*    __restrict__ counter,
    float*       __restrict__ out)
{
    const int t    = threadIdx.x;
    const int sub  = t >> 5;                 // 0..7: row-slot in block
    const int lane = t & 31;                 // lane within 32-lane row group
    const int row  = blockIdx.x * 8 + sub;

    // All 12 indices first (independent loads, one round trip).
    // 10 negatives as 5x int2: (row*NEG*4) % 8 == 0, so 8B-aligned.
    const int2* nb = (const int2*)(neg_idx + (size_t)row * NEG);
    int ni[NEG];
    #pragma unroll
    for (int k = 0; k < NEG / 2; ++k) {
        int2 p = nb[k];
        ni[2 * k] = p.x;
        ni[2 * k + 1] = p.y;
    }
    const int fi = focus_idx[row];
    const int ci = context_idx[row];

    // lane holds elements [4*lane .. 4*lane+3] of the 128-dim embedding
    const float4 f = *(const float4*)(focus_W   + (size_t)fi * DIM + lane * 4);
    const float4 c = *(const float4*)(context_W + (size_t)ci * DIM + lane * 4);

    // neg_score = dot(focus, sum_k context_W[nk]) (einsum summed over K)
    float4 ns = make_float4(0.f, 0.f, 0.f, 0.f);
    #pragma unroll
    for (int k = 0; k < NEG; ++k) {
        const float4 n = *(const float4*)(context_W + (size_t)ni[k] * DIM + lane * 4);
        ns.x += n.x; ns.y += n.y; ns.z += n.z; ns.w += n.w;
    }

    float pos = f.x * c.x  + f.y * c.y  + f.z * c.z  + f.w * c.w;
    float neg = f.x * ns.x + f.y * ns.y + f.z * ns.z + f.w * ns.w;

    // 32-lane butterfly (xor offsets < 32 stay inside each row group)
    #pragma unroll
    for (int off = 16; off > 0; off >>= 1) {
        pos += __shfl_xor(pos, off);
        neg += __shfl_xor(neg, off);
    }

    __shared__ float s[8];
    __shared__ bool  amLast;
    if (lane == 0) {
        float pp = logsig(pos);
        float np = logsig(neg);
        s[sub] = (1.0f - pp) * (1.0f - pp) + np * np;
    }
    __syncthreads();

    if (t == 0) {
        float acc = 0.f;
        #pragma unroll
        for (int i = 0; i < 8; ++i) acc += s[i];
        partial[blockIdx.x] = acc;
        __threadfence();                         // release: partial visible device-wide
        unsigned ticket = atomicAdd(counter, 1u);
        amLast = (ticket == NBLOCK - 1);
    }
    __syncthreads();

    if (amLast) {                                // block-uniform, no divergence hazard
        __threadfence();                         // acquire: see all partials
        float sum = 0.f;
        for (int i = t; i < NBLOCK; i += 256) sum += partial[i];
        #pragma unroll
        for (int off = 32; off > 0; off >>= 1) sum += __shfl_xor(sum, off);
        __shared__ float ws[4];
        if ((t & 63) == 0) ws[t >> 6] = sum;
        __syncthreads();
        if (t == 0) out[0] = (ws[0] + ws[1]) + (ws[2] + ws[3]);
    }
}

extern "C" void kernel_launch(void* const* d_in, const int* in_sizes, int n_in,
                              void* d_out, int out_size, void* d_ws, size_t ws_size,
                              hipStream_t stream) {
    const float* focus_W     = (const float*)d_in[0];
    const float* context_W   = (const float*)d_in[1];
    const int*   focus_idx   = (const int*)d_in[2];
    const int*   context_idx = (const int*)d_in[3];
    const int*   neg_idx     = (const int*)d_in[4];
    float*       out         = (float*)d_out;

    // d_ws layout: [0,4) counter, [256, 256 + NBLOCK*4) partials
    unsigned* counter = (unsigned*)d_ws;
    float*    partial = (float*)((char*)d_ws + 256);

    hipMemsetAsync(counter, 0, sizeof(unsigned), stream);  // capturable node

    sg_fused_kernel<<<NBLOCK, 256, 0, stream>>>(
        focus_W, context_W, focus_idx, context_idx, neg_idx,
        partial, counter, out);
}

// Round 4
// 42.747 us; speedup vs baseline: 2.1412x; 2.1412x over previous
//
#include <hip/hip_runtime.h>
#include <math.h>

#define VOCAB  100000
#define DIM    128
#define BATCH  16384
#define NEG    10
#define NBLOCK (BATCH / 8)   // 2048 blocks, 8 rows each

// Numerically stable log-sigmoid: log(1/(1+e^-x)) = min(x,0) - log1p(e^-|x|)
__device__ __forceinline__ float logsig(float x) {
    float ax = fabsf(x);
    float l  = log1pf(expf(-ax));
    return (x >= 0.0f) ? -l : (x - l);
}

// 32 lanes per batch row (float4/lane = 16B), 2 rows/wave, 8 rows per
// 256-thread block, 2048 blocks = 8192 waves = one fully-resident batch.
// Tail: ONE fence-free global float atomicAdd per block into out[0]
// (out zeroed by a 4-byte hipMemsetAsync each call). No device-scope
// fences — R3 showed per-block __threadfence() costs ~70us on gfx950.
__global__ __launch_bounds__(256) void sg_kernel(
    const float* __restrict__ focus_W,
    const float* __restrict__ context_W,
    const int*   __restrict__ focus_idx,
    const int*   __restrict__ context_idx,
    const int*   __restrict__ neg_idx,
    float*       __restrict__ out)
{
    const int t    = threadIdx.x;
    const int sub  = t >> 5;                 // 0..7: row-slot in block
    const int lane = t & 31;                 // lane within 32-lane row group
    const int row  = blockIdx.x * 8 + sub;

    // All 12 indices first (independent loads, one round trip).
    // 10 negatives as 5x int2: (row*NEG*4) % 8 == 0, so 8B-aligned.
    const int2* nb = (const int2*)(neg_idx + (size_t)row * NEG);
    int ni[NEG];
    #pragma unroll
    for (int k = 0; k < NEG / 2; ++k) {
        int2 p = nb[k];
        ni[2 * k]     = p.x;
        ni[2 * k + 1] = p.y;
    }
    const int fi = focus_idx[row];
    const int ci = context_idx[row];

    // lane holds elements [4*lane .. 4*lane+3] of the 128-dim embedding
    const float4 f = *(const float4*)(focus_W   + (size_t)fi * DIM + lane * 4);
    const float4 c = *(const float4*)(context_W + (size_t)ci * DIM + lane * 4);

    // neg_score = dot(focus, sum_k context_W[nk]) (einsum summed over K)
    float4 ns = make_float4(0.f, 0.f, 0.f, 0.f);
    #pragma unroll
    for (int k = 0; k < NEG; ++k) {
        const float4 n = *(const float4*)(context_W + (size_t)ni[k] * DIM + lane * 4);
        ns.x += n.x; ns.y += n.y; ns.z += n.z; ns.w += n.w;
    }

    float pos = f.x * c.x  + f.y * c.y  + f.z * c.z  + f.w * c.w;
    float neg = f.x * ns.x + f.y * ns.y + f.z * ns.z + f.w * ns.w;

    // 32-lane butterfly (xor offsets < 32 stay inside each row group)
    #pragma unroll
    for (int off = 16; off > 0; off >>= 1) {
        pos += __shfl_xor(pos, off);
        neg += __shfl_xor(neg, off);
    }

    __shared__ float s[8];
    if (lane == 0) {
        float pp = logsig(pos);
        float np = logsig(neg);
        s[sub] = (1.0f - pp) * (1.0f - pp) + np * np;
    }
    __syncthreads();

    if (t == 0) {
        float acc = 0.f;
        #pragma unroll
        for (int i = 0; i < 8; ++i) acc += s[i];
        atomicAdd(out, acc);   // single global_atomic_add_f32, no fence
    }
}

extern "C" void kernel_launch(void* const* d_in, const int* in_sizes, int n_in,
                              void* d_out, int out_size, void* d_ws, size_t ws_size,
                              hipStream_t stream) {
    const float* focus_W     = (const float*)d_in[0];
    const float* context_W   = (const float*)d_in[1];
    const int*   focus_idx   = (const int*)d_in[2];
    const int*   context_idx = (const int*)d_in[3];
    const int*   neg_idx     = (const int*)d_in[4];
    float*       out         = (float*)d_out;

    hipMemsetAsync(out, 0, sizeof(float), stream);  // capturable node

    sg_kernel<<<NBLOCK, 256, 0, stream>>>(
        focus_W, context_W, focus_idx, context_idx, neg_idx, out);
}

// Round 5
// 23.390 us; speedup vs baseline: 3.9132x; 1.8275x over previous
//
#include <hip/hip_runtime.h>
#include <math.h>

#define VOCAB  100000
#define DIM    128
#define BATCH  16384
#define NEG    10
#define NBLOCK (BATCH / 8)   // 2048 blocks, 8 rows each

// Numerically stable log-sigmoid: log(1/(1+e^-x)) = min(x,0) - log1p(e^-|x|)
__device__ __forceinline__ float logsig(float x) {
    float ax = fabsf(x);
    float l  = log1pf(expf(-ax));
    return (x >= 0.0f) ? -l : (x - l);
}

// Stage 1: 32 lanes per batch row (float4/lane = 16B), 2 rows/wave, 8 rows
// per 256-thread block, 2048 blocks = 8192 waves = one fully-resident batch.
// No LDS, no __syncthreads, no atomics: lane 0 of each row group writes the
// row's loss term to partial[row]. (R3/R4 lesson: per-block __threadfence
// costs ~15ns and same-address atomics ~10ns each, serialized -> 20-30us
// for 2048 blocks. Plain stores + a second tiny kernel is the fast path.)
__global__ __launch_bounds__(256) void sg_partial_kernel(
    const float* __restrict__ focus_W,
    const float* __restrict__ context_W,
    const int*   __restrict__ focus_idx,
    const int*   __restrict__ context_idx,
    const int*   __restrict__ neg_idx,
    float*       __restrict__ partial)
{
    const int t    = threadIdx.x;
    const int sub  = t >> 5;                 // 0..7: row-slot in block
    const int lane = t & 31;                 // lane within 32-lane row group
    const int row  = blockIdx.x * 8 + sub;

    // All 12 indices first (independent loads, one round trip).
    // 10 negatives as 5x int2: (row*NEG*4) % 8 == 0, so 8B-aligned.
    const int2* nb = (const int2*)(neg_idx + (size_t)row * NEG);
    int ni[NEG];
    #pragma unroll
    for (int k = 0; k < NEG / 2; ++k) {
        int2 p = nb[k];
        ni[2 * k]     = p.x;
        ni[2 * k + 1] = p.y;
    }
    const int fi = focus_idx[row];
    const int ci = context_idx[row];

    // lane holds elements [4*lane .. 4*lane+3] of the 128-dim embedding
    const float4 f = *(const float4*)(focus_W   + (size_t)fi * DIM + lane * 4);
    const float4 c = *(const float4*)(context_W + (size_t)ci * DIM + lane * 4);

    // neg_score = dot(focus, sum_k context_W[nk]) (einsum summed over K)
    float4 ns = make_float4(0.f, 0.f, 0.f, 0.f);
    #pragma unroll
    for (int k = 0; k < NEG; ++k) {
        const float4 n = *(const float4*)(context_W + (size_t)ni[k] * DIM + lane * 4);
        ns.x += n.x; ns.y += n.y; ns.z += n.z; ns.w += n.w;
    }

    float pos = f.x * c.x  + f.y * c.y  + f.z * c.z  + f.w * c.w;
    float neg = f.x * ns.x + f.y * ns.y + f.z * ns.z + f.w * ns.w;

    // 32-lane butterfly (xor offsets < 32 stay inside each row group)
    #pragma unroll
    for (int off = 16; off > 0; off >>= 1) {
        pos += __shfl_xor(pos, off);
        neg += __shfl_xor(neg, off);
    }

    if (lane == 0) {
        float pp = logsig(pos);
        float np = logsig(neg);
        partial[row] = (1.0f - pp) * (1.0f - pp) + np * np;
    }
}

// Stage 2: one 256-thread block reduces 16384 floats (64KB) -> out[0].
// 16 float4 per thread, fully unrolled independent loads.
__global__ __launch_bounds__(256) void sg_final_kernel(
    const float4* __restrict__ partial, float* __restrict__ out)
{
    const int t = threadIdx.x;
    float s = 0.0f;
    #pragma unroll
    for (int i = 0; i < 16; ++i) {
        float4 p = partial[t + i * 256];      // 4096 float4 total
        s += (p.x + p.y) + (p.z + p.w);
    }

    #pragma unroll
    for (int off = 32; off > 0; off >>= 1) s += __shfl_xor(s, off);

    __shared__ float ws[4];
    if ((t & 63) == 0) ws[t >> 6] = s;
    __syncthreads();
    if (t == 0) out[0] = (ws[0] + ws[1]) + (ws[2] + ws[3]);
}

extern "C" void kernel_launch(void* const* d_in, const int* in_sizes, int n_in,
                              void* d_out, int out_size, void* d_ws, size_t ws_size,
                              hipStream_t stream) {
    const float* focus_W     = (const float*)d_in[0];
    const float* context_W   = (const float*)d_in[1];
    const int*   focus_idx   = (const int*)d_in[2];
    const int*   context_idx = (const int*)d_in[3];
    const int*   neg_idx     = (const int*)d_in[4];
    float*       out         = (float*)d_out;
    float*       partial     = (float*)d_ws;   // 16384 floats = 64KB scratch

    sg_partial_kernel<<<NBLOCK, 256, 0, stream>>>(
        focus_W, context_W, focus_idx, context_idx, neg_idx, partial);
    sg_final_kernel<<<1, 256, 0, stream>>>((const float4*)partial, out);
}